// Round 2
// baseline (243.258 us; speedup 1.0000x reference)
//
#include <hip/hip_runtime.h>
#include <stdint.h>

// BinConv2d: sign(x) conv3x3(pad1) sign(w) + batch-stat BN, integer-exact via
// XNOR-popcount on 128-channel bitplanes.

#define HH 56
#define WW 56
#define CC 128
#define OO 128
#define NIMG 64
#define PIX (HH*WW)               // 3136
#define CNT (NIMG*PIX)            // 200704 per channel
#define TOT ((size_t)NIMG*OO*PIX) // 25690112

// ws layout (bytes)
#define WS_WPACK 0                // 128*9 ulonglong2 = 18432
#define WS_STATS 18432            // 128*{i64,i64}    = 2048
#define WS_SS    20480            // float2[128]      = 1024
#define WS_XPACK 32768            // 64*3136 ulonglong2 = 3211264 (ends 3244032)
#define WS_Y16   3244032          // TOT*int16 = 51380224
#define WS_NEED  (3244032 + (size_t)TOT*2)

__global__ void pack_w_kernel(const float* __restrict__ w, ulonglong2* __restrict__ wpack) {
    int t = blockIdx.x * 256 + threadIdx.x;
    if (t >= OO * 9) return;
    int o = t / 9, tap = t % 9;
    const float* wp = w + (size_t)o * CC * 9 + tap;   // OIHW: stride 9 between in-channels
    unsigned long long lo = 0, hi = 0;
    #pragma unroll 4
    for (int c = 0; c < 64; ++c) lo |= (unsigned long long)(wp[c * 9] > 0.0f) << c;
    #pragma unroll 4
    for (int c = 0; c < 64; ++c) hi |= (unsigned long long)(wp[(c + 64) * 9] > 0.0f) << c;
    wpack[t] = make_ulonglong2(lo, hi);
}

__global__ void pack_x_kernel(const float* __restrict__ x, ulonglong2* __restrict__ xpack) {
    int n = blockIdx.y;
    int p = blockIdx.x * 256 + threadIdx.x;
    if (p >= PIX) return;
    const float* xp = x + (size_t)n * CC * PIX + p;
    unsigned long long lo = 0, hi = 0;
    #pragma unroll 8
    for (int c = 0; c < 64; ++c) lo |= (unsigned long long)(xp[(size_t)c * PIX] > 0.0f) << c;
    #pragma unroll 8
    for (int c = 0; c < 64; ++c) hi |= (unsigned long long)(xp[(size_t)(c + 64) * PIX] > 0.0f) << c;
    xpack[n * PIX + p] = make_ulonglong2(lo, hi);
}

// MODE 0: stats only. MODE 1: stats + y16. MODE 2: normalized float out (fallback).
// Block 256 = 32 channels x 8 wsegs(7px). Grid (4 og, 8 strips(7 rows), 64 n).
// x strip staged in LDS (zeroed halo); 3x3-word register window slid along j with
// compile-time cyclic indexing (full unroll -> no movs); border corrections hoisted per row.
template <int MODE>
__global__ __launch_bounds__(256, 4) void conv_kernel(
    const ulonglong2* __restrict__ xpack,
    const ulonglong2* __restrict__ wpack,
    unsigned long long* stats,
    const float2* __restrict__ ss,
    short* __restrict__ y16,
    float* __restrict__ out)
{
    __shared__ ulonglong2 tile[9][58];   // rows h0-1..h0+7, cols -1..56 (shifted +1)
    __shared__ int s_sum[256];
    __shared__ int s_sq[256];

    const int og = blockIdx.x;
    const int strip = blockIdx.y;
    const int n = blockIdx.z;
    const int tid = threadIdx.x;
    const int o_idx = tid & 31;
    const int wseg = tid >> 5;        // 0..7
    const int o = og * 32 + o_idx;
    const int w0 = wseg * 7;
    const int h0 = strip * 7;

    // stage x strip into LDS (zero halo)
    {
        const ulonglong2* xp = xpack + n * PIX;
        for (int i = tid; i < 9 * 58; i += 256) {
            int r = i / 58, c = i % 58;
            int gr = h0 - 1 + r, gc = c - 1;
            ulonglong2 v = make_ulonglong2(0ULL, 0ULL);
            if (gr >= 0 && gr < HH && gc >= 0 && gc < WW) v = xp[gr * WW + gc];
            tile[r][c] = v;
        }
    }

    ulonglong2 wt[9];
    #pragma unroll
    for (int t = 0; t < 9; ++t) wt[t] = wpack[o * 9 + t];

    int f[9];
    #pragma unroll
    for (int t = 0; t < 9; ++t) f[t] = 128 - 2 * (__popcll(wt[t].x) + __popcll(wt[t].y));
    const int cr0 = f[0] + f[1] + f[2];
    const int cr2 = f[6] + f[7] + f[8];
    const int cc0 = f[0] + f[3] + f[6];
    const int cc2 = f[2] + f[5] + f[8];

    float scale = 0.f, shift = 0.f;
    if (MODE == 2) { float2 v = ss[o]; scale = v.x; shift = v.y; }

    __syncthreads();

    int ysum = 0, ysq = 0;

    for (int hh = 0; hh < 7; ++hh) {
        const int h = h0 + hh;
        // hoisted border corrections (per row, not per output)
        int base = 1152;
        if (h == 0) base -= cr0;
        if (h == HH - 1) base -= cr2;
        int eL = (wseg == 0) ? (cc0 - ((h == 0) ? f[0] : 0) - ((h == HH - 1) ? f[6] : 0)) : 0;
        int eR = (wseg == 7) ? (cc2 - ((h == 0) ? f[2] : 0) - ((h == HH - 1) ? f[8] : 0)) : 0;

        const ulonglong2* trow = &tile[hh][w0];   // window col k of output j = trow[r*58 + j + k]

        ulonglong2 X[3][3];                        // [colmod3][row]
        #pragma unroll
        for (int r = 0; r < 3; ++r) {
            X[0][r] = trow[r * 58 + 0];
            X[1][r] = trow[r * 58 + 1];
        }

        size_t obase = ((size_t)(n * OO + o) * HH + h) * WW + w0;

        #pragma unroll
        for (int j = 0; j < 7; ++j) {
            #pragma unroll
            for (int r = 0; r < 3; ++r) X[(j + 2) % 3][r] = trow[r * 58 + j + 2];

            int m0 = 0, m1 = 0, m2 = 0;   // 3 accumulator chains
            #pragma unroll
            for (int k = 0; k < 3; ++k) {
                ulonglong2 a = X[(j + k) % 3][0];
                m0 += __popcll(a.x ^ wt[k].x) + __popcll(a.y ^ wt[k].y);
                ulonglong2 b = X[(j + k) % 3][1];
                m1 += __popcll(b.x ^ wt[3 + k].x) + __popcll(b.y ^ wt[3 + k].y);
                ulonglong2 c = X[(j + k) % 3][2];
                m2 += __popcll(c.x ^ wt[6 + k].x) + __popcll(c.y ^ wt[6 + k].y);
            }
            int y = base - 2 * (m0 + m1 + m2);
            if (j == 0) y -= eL;
            if (j == 6) y -= eR;

            if (MODE != 2) { ysum += y; ysq += y * y; }
            if (MODE == 1) y16[obase + j] = (short)y;
            if (MODE == 2) out[obase + j] = (float)y * scale + shift;
        }
    }

    if (MODE != 2) {
        s_sum[tid] = ysum;
        s_sq[tid] = ysq;
        __syncthreads();
        if (tid < 32) {
            long long ts = 0, tq = 0;
            #pragma unroll
            for (int k = 0; k < 8; ++k) { ts += s_sum[tid + 32 * k]; tq += s_sq[tid + 32 * k]; }
            int oo = og * 32 + tid;
            atomicAdd(&stats[oo * 2 + 0], (unsigned long long)ts);
            atomicAdd(&stats[oo * 2 + 1], (unsigned long long)tq);
        }
    }
}

__global__ void finalize_kernel(const unsigned long long* __restrict__ stats,
                                const float* __restrict__ gamma,
                                const float* __restrict__ beta,
                                float2* __restrict__ ss) {
    int c = threadIdx.x;
    if (c >= 128) return;
    long long s = (long long)stats[c * 2 + 0];
    long long q = (long long)stats[c * 2 + 1];
    double mean = (double)s / (double)CNT;
    double var = (double)q / (double)CNT - mean * mean;
    double inv = 1.0 / sqrt(var + 1e-5);
    double g = (double)gamma[c];
    float sc = (float)(g * inv);
    float sh = (float)((double)beta[c] - mean * g * inv);
    ss[c] = make_float2(sc, sh);
}

// 8 elements/thread; 3136 % 8 == 0 so a group never crosses a channel boundary.
__global__ void norm_kernel(const short* __restrict__ y16,
                            const float2* __restrict__ ss,
                            float* __restrict__ out) {
    size_t g = (size_t)blockIdx.x * 256 + threadIdx.x;
    size_t e = g * 8;
    unsigned int chan = (unsigned int)((e / PIX) & 127);
    float2 v = ss[chan];
    int4 raw = *reinterpret_cast<const int4*>(y16 + e);
    float4 o0, o1;
    o0.x = (float)(short)(raw.x & 0xffff) * v.x + v.y;
    o0.y = (float)(short)(raw.x >> 16)    * v.x + v.y;
    o0.z = (float)(short)(raw.y & 0xffff) * v.x + v.y;
    o0.w = (float)(short)(raw.y >> 16)    * v.x + v.y;
    o1.x = (float)(short)(raw.z & 0xffff) * v.x + v.y;
    o1.y = (float)(short)(raw.z >> 16)    * v.x + v.y;
    o1.z = (float)(short)(raw.w & 0xffff) * v.x + v.y;
    o1.w = (float)(short)(raw.w >> 16)    * v.x + v.y;
    *reinterpret_cast<float4*>(out + e) = o0;
    *reinterpret_cast<float4*>(out + e + 4) = o1;
}

extern "C" void kernel_launch(void* const* d_in, const int* in_sizes, int n_in,
                              void* d_out, int out_size, void* d_ws, size_t ws_size,
                              hipStream_t stream) {
    const float* x     = (const float*)d_in[0];
    const float* wgt   = (const float*)d_in[1];
    const float* gamma = (const float*)d_in[2];
    const float* beta  = (const float*)d_in[3];
    float* out = (float*)d_out;
    char* ws = (char*)d_ws;

    ulonglong2* wpack = (ulonglong2*)(ws + WS_WPACK);
    unsigned long long* stats = (unsigned long long*)(ws + WS_STATS);
    float2* ss = (float2*)(ws + WS_SS);
    ulonglong2* xpack = (ulonglong2*)(ws + WS_XPACK);
    short* y16 = (short*)(ws + WS_Y16);

    hipMemsetAsync(stats, 0, 2048, stream);
    pack_w_kernel<<<5, 256, 0, stream>>>(wgt, wpack);
    pack_x_kernel<<<dim3(13, 64), 256, 0, stream>>>(x, xpack);

    if (ws_size >= WS_NEED) {
        conv_kernel<1><<<dim3(4, 8, 64), 256, 0, stream>>>(xpack, wpack, stats, nullptr, y16, nullptr);
        finalize_kernel<<<1, 128, 0, stream>>>(stats, gamma, beta, ss);
        norm_kernel<<<(unsigned)(TOT / 8 / 256), 256, 0, stream>>>(y16, ss, out);
    } else {
        conv_kernel<0><<<dim3(4, 8, 64), 256, 0, stream>>>(xpack, wpack, stats, nullptr, nullptr, nullptr);
        finalize_kernel<<<1, 128, 0, stream>>>(stats, gamma, beta, ss);
        conv_kernel<2><<<dim3(4, 8, 64), 256, 0, stream>>>(xpack, wpack, stats, ss, nullptr, out);
    }
}

// Round 3
// 171.671 us; speedup vs baseline: 1.4170x; 1.4170x over previous
//
#include <hip/hip_runtime.h>
#include <stdint.h>

// BinConv2d: sign(x) conv3x3(pad1) sign(w) + batch-stat BN, integer-exact via
// XNOR-popcount on 128-channel bitplanes.

#define HH 56
#define WW 56
#define CC 128
#define OO 128
#define NIMG 64
#define PIX (HH*WW)               // 3136
#define CNT (NIMG*PIX)            // 200704 per channel
#define TOT ((size_t)NIMG*OO*PIX) // 25690112

// ws layout (bytes)
#define WS_WPACK 0                // 128*9 ulonglong2 = 18432
#define WS_STATS 18432            // 128*{i64,i64}    = 2048
#define WS_SS    20480            // float2[128]      = 1024
#define WS_XPACK 32768            // 64*3136 ulonglong2 = 3211264 (ends 3244032)
#define WS_Y16   3244032          // TOT*int16 = 51380224
#define WS_NEED  (3244032 + (size_t)TOT*2)

__global__ void pack_w_kernel(const float* __restrict__ w, ulonglong2* __restrict__ wpack) {
    int t = blockIdx.x * 256 + threadIdx.x;
    if (t >= OO * 9) return;
    int o = t / 9, tap = t % 9;
    const float* wp = w + (size_t)o * CC * 9 + tap;   // OIHW: stride 9 between in-channels
    unsigned long long lo = 0, hi = 0;
    #pragma unroll 4
    for (int c = 0; c < 64; ++c) lo |= (unsigned long long)(wp[c * 9] > 0.0f) << c;
    #pragma unroll 4
    for (int c = 0; c < 64; ++c) hi |= (unsigned long long)(wp[(c + 64) * 9] > 0.0f) << c;
    wpack[t] = make_ulonglong2(lo, hi);
}

__global__ void pack_x_kernel(const float* __restrict__ x, ulonglong2* __restrict__ xpack) {
    int n = blockIdx.y;
    int p = blockIdx.x * 256 + threadIdx.x;
    if (p >= PIX) return;
    const float* xp = x + (size_t)n * CC * PIX + p;
    unsigned long long lo = 0, hi = 0;
    #pragma unroll 8
    for (int c = 0; c < 64; ++c) lo |= (unsigned long long)(xp[(size_t)c * PIX] > 0.0f) << c;
    #pragma unroll 8
    for (int c = 0; c < 64; ++c) hi |= (unsigned long long)(xp[(size_t)(c + 64) * PIX] > 0.0f) << c;
    xpack[n * PIX + p] = make_ulonglong2(lo, hi);
}

// Apply tile row R: each x-word feeds up to 3 weight-rows r (out row hl = R-r) x
// 3 weight-cols k (out col j = i-k). Accumulator slot = hl % 3. All indices
// compile-time (R template, loops unrolled) -> arrays stay in registers.
template <int R>
__device__ __forceinline__ void row_apply(const ulonglong2* __restrict__ trow,
                                          const ulonglong2 (&wt)[9],
                                          int (&a0)[7], int (&a1)[7], int (&a2)[7]) {
    #pragma unroll
    for (int i = 0; i < 9; ++i) {
        ulonglong2 xw = trow[i];
        #pragma unroll
        for (int r = 0; r < 3; ++r) {
            if (R - r < 0 || R - r > 6) continue;         // out-row outside strip: skip statically
            const int s = (R - r) % 3;
            #pragma unroll
            for (int k = 0; k < 3; ++k) {
                const int j = i - k;
                if (j < 0 || j > 6) continue;
                int add = __popcll(xw.x ^ wt[3 * r + k].x) + __popcll(xw.y ^ wt[3 * r + k].y);
                if (s == 0) a0[j] += add;
                else if (s == 1) a1[j] += add;
                else a2[j] += add;
            }
        }
    }
}

// MODE 0: stats only. MODE 1: stats + y16. MODE 2: normalized float out (fallback).
// Block 256 = 32 channels (tid>>3) x 8 wsegs (tid&7, 7 px each). Grid (4 og, 8 strips, 64 n).
// x strip (9x58 words, zero halo) in LDS; rolling 3x7 partial-sum rows; R-loop fully unrolled.
template <int MODE>
__global__ __launch_bounds__(256, 2) void conv_kernel(
    const ulonglong2* __restrict__ xpack,
    const ulonglong2* __restrict__ wpack,
    unsigned long long* stats,
    const float2* __restrict__ ss,
    short* __restrict__ y16,
    float* __restrict__ out)
{
    __shared__ ulonglong2 tile[9][58];   // rows h0-1..h0+7, cols -1..56 (shifted +1)
    __shared__ int s_sum[256];
    __shared__ int s_sq[256];

    const int og = blockIdx.x;
    const int strip = blockIdx.y;
    const int n = blockIdx.z;
    const int tid = threadIdx.x;
    const int wseg = tid & 7;          // 0..7 -> w0 = wseg*7
    const int o_idx = tid >> 3;        // 0..31
    const int o = og * 32 + o_idx;
    const int w0 = wseg * 7;
    const int h0 = strip * 7;

    // stage x strip into LDS (zero halo)
    {
        const ulonglong2* xp = xpack + n * PIX;
        #pragma unroll
        for (int ii = 0; ii < 3; ++ii) {
            int i = tid + ii * 256;
            if (i < 9 * 58) {
                int r = i / 58, c = i % 58;
                int gr = h0 - 1 + r, gc = c - 1;
                ulonglong2 v = make_ulonglong2(0ULL, 0ULL);
                if (gr >= 0 && gr < HH && gc >= 0 && gc < WW) v = xp[gr * WW + gc];
                tile[r][c] = v;
            }
        }
    }

    ulonglong2 wt[9];
    #pragma unroll
    for (int t = 0; t < 9; ++t) wt[t] = wpack[o * 9 + t];

    int f[9];
    #pragma unroll
    for (int t = 0; t < 9; ++t) f[t] = 128 - 2 * (__popcll(wt[t].x) + __popcll(wt[t].y));
    const int cr0 = f[0] + f[1] + f[2];
    const int cr2 = f[6] + f[7] + f[8];
    const int cc0 = f[0] + f[3] + f[6];
    const int cc2 = f[2] + f[5] + f[8];

    float scale = 0.f, shift = 0.f;
    if (MODE == 2) { float2 v = ss[o]; scale = v.x; shift = v.y; }

    __syncthreads();

    int a0[7], a1[7], a2[7];
    #pragma unroll
    for (int j = 0; j < 7; ++j) { a0[j] = 0; a1[j] = 0; a2[j] = 0; }
    int ysum = 0, ysq = 0;

    const ulonglong2* tbase = &tile[0][w0];

    auto emit = [&](int (&acc)[7], int hl) {
        const int h = h0 + hl;
        int base = 1152;
        if (h == 0) base -= cr0;
        if (h == HH - 1) base -= cr2;
        const int eL = (wseg == 0) ? (cc0 - ((h == 0) ? f[0] : 0) - ((h == HH - 1) ? f[6] : 0)) : 0;
        const int eR = (wseg == 7) ? (cc2 - ((h == 0) ? f[2] : 0) - ((h == HH - 1) ? f[8] : 0)) : 0;
        size_t obase = ((size_t)(n * OO + o) * HH + h) * WW + w0;
        #pragma unroll
        for (int j = 0; j < 7; ++j) {
            int y = base - 2 * acc[j];
            if (j == 0) y -= eL;
            if (j == 6) y -= eR;
            if (MODE != 2) { ysum += y; ysq += y * y; }
            if (MODE == 1) y16[obase + j] = (short)y;
            if (MODE == 2) out[obase + j] = (float)y * scale + shift;
            acc[j] = 0;
        }
    };

    row_apply<0>(tbase + 0 * 58, wt, a0, a1, a2);
    row_apply<1>(tbase + 1 * 58, wt, a0, a1, a2);
    row_apply<2>(tbase + 2 * 58, wt, a0, a1, a2); emit(a0, 0);
    row_apply<3>(tbase + 3 * 58, wt, a0, a1, a2); emit(a1, 1);
    row_apply<4>(tbase + 4 * 58, wt, a0, a1, a2); emit(a2, 2);
    row_apply<5>(tbase + 5 * 58, wt, a0, a1, a2); emit(a0, 3);
    row_apply<6>(tbase + 6 * 58, wt, a0, a1, a2); emit(a1, 4);
    row_apply<7>(tbase + 7 * 58, wt, a0, a1, a2); emit(a2, 5);
    row_apply<8>(tbase + 8 * 58, wt, a0, a1, a2); emit(a0, 6);

    if (MODE != 2) {
        s_sum[tid] = ysum;
        s_sq[tid] = ysq;
        __syncthreads();
        if (tid < 32) {
            long long ts = 0, tq = 0;
            #pragma unroll
            for (int k = 0; k < 8; ++k) { ts += s_sum[tid * 8 + k]; tq += s_sq[tid * 8 + k]; }
            int oo = og * 32 + tid;
            atomicAdd(&stats[oo * 2 + 0], (unsigned long long)ts);
            atomicAdd(&stats[oo * 2 + 1], (unsigned long long)tq);
        }
    }
}

__global__ void finalize_kernel(const unsigned long long* __restrict__ stats,
                                const float* __restrict__ gamma,
                                const float* __restrict__ beta,
                                float2* __restrict__ ss) {
    int c = threadIdx.x;
    if (c >= 128) return;
    long long s = (long long)stats[c * 2 + 0];
    long long q = (long long)stats[c * 2 + 1];
    double mean = (double)s / (double)CNT;
    double var = (double)q / (double)CNT - mean * mean;
    double inv = 1.0 / sqrt(var + 1e-5);
    double g = (double)gamma[c];
    float sc = (float)(g * inv);
    float sh = (float)((double)beta[c] - mean * g * inv);
    ss[c] = make_float2(sc, sh);
}

// 8 elements/thread; 3136 % 8 == 0 so a group never crosses a channel boundary.
__global__ void norm_kernel(const short* __restrict__ y16,
                            const float2* __restrict__ ss,
                            float* __restrict__ out) {
    size_t g = (size_t)blockIdx.x * 256 + threadIdx.x;
    size_t e = g * 8;
    unsigned int chan = (unsigned int)((e / PIX) & 127);
    float2 v = ss[chan];
    int4 raw = *reinterpret_cast<const int4*>(y16 + e);
    float4 o0, o1;
    o0.x = (float)(short)(raw.x & 0xffff) * v.x + v.y;
    o0.y = (float)(short)(raw.x >> 16)    * v.x + v.y;
    o0.z = (float)(short)(raw.y & 0xffff) * v.x + v.y;
    o0.w = (float)(short)(raw.y >> 16)    * v.x + v.y;
    o1.x = (float)(short)(raw.z & 0xffff) * v.x + v.y;
    o1.y = (float)(short)(raw.z >> 16)    * v.x + v.y;
    o1.z = (float)(short)(raw.w & 0xffff) * v.x + v.y;
    o1.w = (float)(short)(raw.w >> 16)    * v.x + v.y;
    *reinterpret_cast<float4*>(out + e) = o0;
    *reinterpret_cast<float4*>(out + e + 4) = o1;
}

extern "C" void kernel_launch(void* const* d_in, const int* in_sizes, int n_in,
                              void* d_out, int out_size, void* d_ws, size_t ws_size,
                              hipStream_t stream) {
    const float* x     = (const float*)d_in[0];
    const float* wgt   = (const float*)d_in[1];
    const float* gamma = (const float*)d_in[2];
    const float* beta  = (const float*)d_in[3];
    float* out = (float*)d_out;
    char* ws = (char*)d_ws;

    ulonglong2* wpack = (ulonglong2*)(ws + WS_WPACK);
    unsigned long long* stats = (unsigned long long*)(ws + WS_STATS);
    float2* ss = (float2*)(ws + WS_SS);
    ulonglong2* xpack = (ulonglong2*)(ws + WS_XPACK);
    short* y16 = (short*)(ws + WS_Y16);

    hipMemsetAsync(stats, 0, 2048, stream);
    pack_w_kernel<<<5, 256, 0, stream>>>(wgt, wpack);
    pack_x_kernel<<<dim3(13, 64), 256, 0, stream>>>(x, xpack);

    if (ws_size >= WS_NEED) {
        conv_kernel<1><<<dim3(4, 8, 64), 256, 0, stream>>>(xpack, wpack, stats, nullptr, y16, nullptr);
        finalize_kernel<<<1, 128, 0, stream>>>(stats, gamma, beta, ss);
        norm_kernel<<<(unsigned)(TOT / 8 / 256), 256, 0, stream>>>(y16, ss, out);
    } else {
        conv_kernel<0><<<dim3(4, 8, 64), 256, 0, stream>>>(xpack, wpack, stats, nullptr, nullptr, nullptr);
        finalize_kernel<<<1, 128, 0, stream>>>(stats, gamma, beta, ss);
        conv_kernel<2><<<dim3(4, 8, 64), 256, 0, stream>>>(xpack, wpack, stats, ss, nullptr, out);
    }
}

// Round 4
// 140.699 us; speedup vs baseline: 1.7289x; 1.2201x over previous
//
#include <hip/hip_runtime.h>
#include <stdint.h>

// BinConv2d: sign(x) conv3x3(pad1) sign(w) + batch-stat BN, integer-exact via
// XNOR-popcount on 128-channel bitplanes.

#define HH 56
#define WW 56
#define CC 128
#define OO 128
#define NIMG 64
#define PIX (HH*WW)               // 3136
#define CNT (NIMG*PIX)            // 200704 per channel
#define TOT ((size_t)NIMG*OO*PIX) // 25690112

// ws layout (bytes)
#define WS_WPACK 0                // 128*9 ulonglong2 = 18432
#define WS_STATS 18432            // 128*{i64,i64}    = 2048
#define WS_SS    20480            // float2[128]      = 1024
#define WS_XPACK 32768            // 64*3136 ulonglong2 = 3211264 (ends 3244032)
#define WS_Y16   3244032          // TOT*int16 = 51380224
#define WS_NEED  (3244032 + (size_t)TOT*2)

__global__ void pack_w_kernel(const float* __restrict__ w, ulonglong2* __restrict__ wpack) {
    int t = blockIdx.x * 256 + threadIdx.x;
    if (t >= OO * 9) return;
    int o = t / 9, tap = t % 9;
    const float* wp = w + (size_t)o * CC * 9 + tap;   // OIHW: stride 9 between in-channels
    unsigned long long lo = 0, hi = 0;
    #pragma unroll 4
    for (int c = 0; c < 64; ++c) lo |= (unsigned long long)(wp[c * 9] > 0.0f) << c;
    #pragma unroll 4
    for (int c = 0; c < 64; ++c) hi |= (unsigned long long)(wp[(c + 64) * 9] > 0.0f) << c;
    wpack[t] = make_ulonglong2(lo, hi);
}

__global__ void pack_x_kernel(const float* __restrict__ x, ulonglong2* __restrict__ xpack) {
    int n = blockIdx.y;
    int p = blockIdx.x * 256 + threadIdx.x;
    if (p >= PIX) return;
    const float* xp = x + (size_t)n * CC * PIX + p;
    unsigned long long lo = 0, hi = 0;
    #pragma unroll 8
    for (int c = 0; c < 64; ++c) lo |= (unsigned long long)(xp[(size_t)c * PIX] > 0.0f) << c;
    #pragma unroll 8
    for (int c = 0; c < 64; ++c) hi |= (unsigned long long)(xp[(size_t)(c + 64) * PIX] > 0.0f) << c;
    xpack[n * PIX + p] = make_ulonglong2(lo, hi);
}

// MODE 0: stats only. MODE 1: stats + y16. MODE 2: normalized float out (fallback).
// Block 256 = 32 channels (tid&31) x 8 wsegs (tid>>5, 7 px each). Grid (4 og, 8 strips(7 rows), 64 n).
// x strip (9x58 words, zero halo) staged in LDS; 3x3-word register window slid along j
// with compile-time cyclic indexing (j fully unrolled); border corrections hoisted per row.
// NOTE: launch_bounds min-waves MUST stay at 2 (4 forced a 64-VGPR target -> scratch spill, R2),
// and no arrays may be passed by reference (address-taken -> SROA failure -> scratch, R3).
template <int MODE>
__global__ __launch_bounds__(256, 2) void conv_kernel(
    const ulonglong2* __restrict__ xpack,
    const ulonglong2* __restrict__ wpack,
    unsigned long long* stats,
    const float2* __restrict__ ss,
    short* __restrict__ y16,
    float* __restrict__ out)
{
    __shared__ ulonglong2 tile[9][58];   // rows h0-1..h0+7, cols -1..56 (shifted +1)
    __shared__ int s_sum[256];
    __shared__ int s_sq[256];

    const int og = blockIdx.x;
    const int strip = blockIdx.y;
    const int n = blockIdx.z;
    const int tid = threadIdx.x;
    const int o_idx = tid & 31;
    const int wseg = tid >> 5;        // 0..7
    const int o = og * 32 + o_idx;
    const int w0 = wseg * 7;
    const int h0 = strip * 7;

    // stage x strip into LDS (zero halo) — straight-line, no lambda
    {
        const ulonglong2* xp = xpack + n * PIX;
        #pragma unroll
        for (int ii = 0; ii < 3; ++ii) {
            int i = tid + ii * 256;
            if (i < 9 * 58) {
                int r = i / 58, c = i % 58;
                int gr = h0 - 1 + r, gc = c - 1;
                ulonglong2 v = make_ulonglong2(0ULL, 0ULL);
                if (gr >= 0 && gr < HH && gc >= 0 && gc < WW) v = xp[gr * WW + gc];
                tile[r][c] = v;
            }
        }
    }

    ulonglong2 wt[9];
    #pragma unroll
    for (int t = 0; t < 9; ++t) wt[t] = wpack[o * 9 + t];

    int f[9];
    #pragma unroll
    for (int t = 0; t < 9; ++t) f[t] = 128 - 2 * (__popcll(wt[t].x) + __popcll(wt[t].y));
    const int cr0 = f[0] + f[1] + f[2];
    const int cr2 = f[6] + f[7] + f[8];
    const int cc0 = f[0] + f[3] + f[6];
    const int cc2 = f[2] + f[5] + f[8];

    float scale = 0.f, shift = 0.f;
    if (MODE == 2) { float2 v = ss[o]; scale = v.x; shift = v.y; }

    __syncthreads();

    int ysum = 0, ysq = 0;

    for (int hh = 0; hh < 7; ++hh) {
        const int h = h0 + hh;
        // hoisted border corrections (per row, not per output)
        int base = 1152;
        if (h == 0) base -= cr0;
        if (h == HH - 1) base -= cr2;
        const int eL = (wseg == 0) ? (cc0 - ((h == 0) ? f[0] : 0) - ((h == HH - 1) ? f[6] : 0)) : 0;
        const int eR = (wseg == 7) ? (cc2 - ((h == 0) ? f[2] : 0) - ((h == HH - 1) ? f[8] : 0)) : 0;

        const ulonglong2* trow = &tile[hh][w0];   // window col k of output j = trow[r*58 + j + k]

        ulonglong2 X[3][3];                        // [colmod3][row] — all indices compile-time
        #pragma unroll
        for (int r = 0; r < 3; ++r) {
            X[0][r] = trow[r * 58 + 0];
            X[1][r] = trow[r * 58 + 1];
        }

        size_t obase = ((size_t)(n * OO + o) * HH + h) * WW + w0;

        #pragma unroll
        for (int j = 0; j < 7; ++j) {
            #pragma unroll
            for (int r = 0; r < 3; ++r) X[(j + 2) % 3][r] = trow[r * 58 + j + 2];

            int m0 = 0, m1 = 0, m2 = 0;   // 3 accumulator chains for ILP
            #pragma unroll
            for (int k = 0; k < 3; ++k) {
                ulonglong2 a = X[(j + k) % 3][0];
                m0 += __popcll(a.x ^ wt[k].x) + __popcll(a.y ^ wt[k].y);
                ulonglong2 b = X[(j + k) % 3][1];
                m1 += __popcll(b.x ^ wt[3 + k].x) + __popcll(b.y ^ wt[3 + k].y);
                ulonglong2 c = X[(j + k) % 3][2];
                m2 += __popcll(c.x ^ wt[6 + k].x) + __popcll(c.y ^ wt[6 + k].y);
            }
            int y = base - 2 * (m0 + m1 + m2);
            if (j == 0) y -= eL;
            if (j == 6) y -= eR;

            if (MODE != 2) { ysum += y; ysq += y * y; }
            if (MODE == 1) y16[obase + j] = (short)y;
            if (MODE == 2) out[obase + j] = (float)y * scale + shift;
        }
    }

    if (MODE != 2) {
        s_sum[tid] = ysum;
        s_sq[tid] = ysq;
        __syncthreads();
        if (tid < 32) {
            long long ts = 0, tq = 0;
            #pragma unroll
            for (int k = 0; k < 8; ++k) { ts += s_sum[tid + 32 * k]; tq += s_sq[tid + 32 * k]; }
            int oo = og * 32 + tid;
            atomicAdd(&stats[oo * 2 + 0], (unsigned long long)ts);
            atomicAdd(&stats[oo * 2 + 1], (unsigned long long)tq);
        }
    }
}

__global__ void finalize_kernel(const unsigned long long* __restrict__ stats,
                                const float* __restrict__ gamma,
                                const float* __restrict__ beta,
                                float2* __restrict__ ss) {
    int c = threadIdx.x;
    if (c >= 128) return;
    long long s = (long long)stats[c * 2 + 0];
    long long q = (long long)stats[c * 2 + 1];
    double mean = (double)s / (double)CNT;
    double var = (double)q / (double)CNT - mean * mean;
    double inv = 1.0 / sqrt(var + 1e-5);
    double g = (double)gamma[c];
    float sc = (float)(g * inv);
    float sh = (float)((double)beta[c] - mean * g * inv);
    ss[c] = make_float2(sc, sh);
}

// 8 elements/thread; 3136 % 8 == 0 so a group never crosses a channel boundary.
__global__ void norm_kernel(const short* __restrict__ y16,
                            const float2* __restrict__ ss,
                            float* __restrict__ out) {
    size_t g = (size_t)blockIdx.x * 256 + threadIdx.x;
    size_t e = g * 8;
    unsigned int chan = (unsigned int)((e / PIX) & 127);
    float2 v = ss[chan];
    int4 raw = *reinterpret_cast<const int4*>(y16 + e);
    float4 o0, o1;
    o0.x = (float)(short)(raw.x & 0xffff) * v.x + v.y;
    o0.y = (float)(short)(raw.x >> 16)    * v.x + v.y;
    o0.z = (float)(short)(raw.y & 0xffff) * v.x + v.y;
    o0.w = (float)(short)(raw.y >> 16)    * v.x + v.y;
    o1.x = (float)(short)(raw.z & 0xffff) * v.x + v.y;
    o1.y = (float)(short)(raw.z >> 16)    * v.x + v.y;
    o1.z = (float)(short)(raw.w & 0xffff) * v.x + v.y;
    o1.w = (float)(short)(raw.w >> 16)    * v.x + v.y;
    *reinterpret_cast<float4*>(out + e) = o0;
    *reinterpret_cast<float4*>(out + e + 4) = o1;
}

extern "C" void kernel_launch(void* const* d_in, const int* in_sizes, int n_in,
                              void* d_out, int out_size, void* d_ws, size_t ws_size,
                              hipStream_t stream) {
    const float* x     = (const float*)d_in[0];
    const float* wgt   = (const float*)d_in[1];
    const float* gamma = (const float*)d_in[2];
    const float* beta  = (const float*)d_in[3];
    float* out = (float*)d_out;
    char* ws = (char*)d_ws;

    ulonglong2* wpack = (ulonglong2*)(ws + WS_WPACK);
    unsigned long long* stats = (unsigned long long*)(ws + WS_STATS);
    float2* ss = (float2*)(ws + WS_SS);
    ulonglong2* xpack = (ulonglong2*)(ws + WS_XPACK);
    short* y16 = (short*)(ws + WS_Y16);

    hipMemsetAsync(stats, 0, 2048, stream);
    pack_w_kernel<<<5, 256, 0, stream>>>(wgt, wpack);
    pack_x_kernel<<<dim3(13, 64), 256, 0, stream>>>(x, xpack);

    if (ws_size >= WS_NEED) {
        conv_kernel<1><<<dim3(4, 8, 64), 256, 0, stream>>>(xpack, wpack, stats, nullptr, y16, nullptr);
        finalize_kernel<<<1, 128, 0, stream>>>(stats, gamma, beta, ss);
        norm_kernel<<<(unsigned)(TOT / 8 / 256), 256, 0, stream>>>(y16, ss, out);
    } else {
        conv_kernel<0><<<dim3(4, 8, 64), 256, 0, stream>>>(xpack, wpack, stats, nullptr, nullptr, nullptr);
        finalize_kernel<<<1, 128, 0, stream>>>(stats, gamma, beta, ss);
        conv_kernel<2><<<dim3(4, 8, 64), 256, 0, stream>>>(xpack, wpack, stats, ss, nullptr, out);
    }
}